// Round 12
// baseline (35.184 us; speedup 1.0000x reference)
//
#include <hip/hip_runtime.h>

#define GRAV_EPS 0.01f
#define NMAX_LDS 50048   // LDS tables: u16 mass (100,096B) + u8 norm (50,048B) = 146.6 KB

typedef float v2f __attribute__((ext_vector_type(2)));

// e2m1 mag-code -> fp8(e4m3) byte LUT for v_perm:
//  mag {0,0.5,1,1.5, 2,3,4,6} -> {0x00,0x30,0x38,0x3C, 0x40,0x44,0x48,0x4C}
#define T0_LUT 0x3C383000u
#define T1_LUT 0x4C484440u

// ---- Repack: x[N][129] f32 -> posf4[N][64B] e2m1 nibbles
//   + nm[N] float2 {exact norm, mass}  (fallback path)
//   + gnorm8[N] u8 (norm-32, quantum 1.0), gmass16[N] u16 ((m+8)*4096)  (LDS path)
// Scalar x loads only (rows are 4B-aligned; float4 casts are UB — R9 lesson).
__global__ __launch_bounds__(256) void grav_repack_fp4(
    const float*    __restrict__ x,
    unsigned int*   __restrict__ posf4,   // N*16 dwords
    float2*         __restrict__ nm,
    unsigned char*  __restrict__ gnorm8,
    unsigned short* __restrict__ gmass16,
    long total_words, int N)
{
    long w = (long)blockIdx.x * blockDim.x + threadIdx.x;
    if (w >= total_words) return;
    int row = (int)(w >> 4);
    int c   = (int)(w & 15);
    const float* src = x + (long)row * 129 + c * 8;

    float nsum = 0.0f;
    unsigned int word = 0;
    #pragma unroll
    for (int j = 0; j < 8; ++j) {
        float v  = src[j];              // scalar, 4B-aligned: well-defined
        nsum = fmaf(v, v, nsum);
        float av = fabsf(v);
        unsigned int m = (av >= 0.25f) + (av >= 0.75f) + (av >= 1.25f) +
                         (av >= 1.75f) + (av >= 2.5f)  + (av >= 3.5f)  +
                         (av >= 5.0f);
        unsigned int nib = m | (v < 0.0f ? 8u : 0u);
        word |= nib << (4 * j);
    }
    posf4[w] = word;

    // exact row norm: reduce across the 16 dword-threads of this row
    nsum += __shfl_xor(nsum, 1);
    nsum += __shfl_xor(nsum, 2);
    nsum += __shfl_xor(nsum, 4);
    nsum += __shfl_xor(nsum, 8);
    if (c == 0) {
        float m = x[(long)row * 129 + 128];
        nm[row] = make_float2(nsum, m);
        int nq = (int)rintf(nsum - 32.0f);
        nq = nq < 0 ? 0 : (nq > 255 ? 255 : nq);
        gnorm8[row] = (unsigned char)nq;
        int mq = (int)rintf((m + 8.0f) * 4096.0f);
        mq = mq < 0 ? 0 : (mq > 65535 ? 65535 : mq);
        gmass16[row] = (unsigned short)mq;
    }
}

// Decode one fp4-nibble dword pair and accumulate dot product (8 elems).
__device__ inline void dot_dword(unsigned int wa, unsigned int wb, v2f& acc)
{
    unsigned int ame = wa & 0x07070707u;
    unsigned int amo = (wa >> 4) & 0x07070707u;
    unsigned int ase = (wa & 0x08080808u) << 4;
    unsigned int aso = wa & 0x80808080u;
    unsigned int pae = __builtin_amdgcn_perm(T1_LUT, T0_LUT, ame) | ase;
    unsigned int pao = __builtin_amdgcn_perm(T1_LUT, T0_LUT, amo) | aso;

    unsigned int bme = wb & 0x07070707u;
    unsigned int bmo = (wb >> 4) & 0x07070707u;
    unsigned int bse = (wb & 0x08080808u) << 4;
    unsigned int bso = wb & 0x80808080u;
    unsigned int pbe = __builtin_amdgcn_perm(T1_LUT, T0_LUT, bme) | bse;
    unsigned int pbo = __builtin_amdgcn_perm(T1_LUT, T0_LUT, bmo) | bso;

    v2f a0 = __builtin_amdgcn_cvt_pk_f32_fp8((int)pae, false);
    v2f a1 = __builtin_amdgcn_cvt_pk_f32_fp8((int)pae, true);
    v2f a2 = __builtin_amdgcn_cvt_pk_f32_fp8((int)pao, false);
    v2f a3 = __builtin_amdgcn_cvt_pk_f32_fp8((int)pao, true);
    v2f b0 = __builtin_amdgcn_cvt_pk_f32_fp8((int)pbe, false);
    v2f b1 = __builtin_amdgcn_cvt_pk_f32_fp8((int)pbe, true);
    v2f b2 = __builtin_amdgcn_cvt_pk_f32_fp8((int)pbo, false);
    v2f b3 = __builtin_amdgcn_cvt_pk_f32_fp8((int)pbo, true);

    acc += a0 * b0;
    acc += a1 * b1;
    acc += a2 * b2;
    acc += a3 * b3;
}

__device__ inline float edge_dot(const uint4& A, const uint4& B)
{
    v2f acc = {0.0f, 0.0f};
    dot_dword(A.x, B.x, acc);
    dot_dword(A.y, B.y, acc);
    dot_dword(A.z, B.z, acc);
    dot_dword(A.w, B.w, acc);
    return acc.x + acc.y;
}

// ---- Main (LDS variant): norm/mass tables live in LDS -> only 2 random
// granules per edge (the two 64B fp4 rows). 1 block/CU, grid-stride edges.
__global__ __launch_bounds__(1024, 1) void DecoderGravity_33268816675213_kernel(
    const uint4*          __restrict__ posf4,
    const unsigned char*  __restrict__ gnorm8,
    const unsigned short* __restrict__ gmass16,
    const int*            __restrict__ eli,
    const float*          __restrict__ lp,
    float*                __restrict__ out,
    int E, int N)
{
    __shared__ unsigned short massT[NMAX_LDS];
    __shared__ unsigned char  normT[NMAX_LDS];

    for (int i = threadIdx.x; i < N; i += 1024) {
        massT[i] = gmass16[i];
        normT[i] = gnorm8[i];
    }
    __syncthreads();

    int lane = threadIdx.x & 3;
    int g    = threadIdx.x >> 2;            // 0..255 edge-groups per block
    int chunk = (E + (int)gridDim.x - 1) / (int)gridDim.x;
    int e_lo = (int)blockIdx.x * chunk;
    int e_hi = e_lo + chunk; if (e_hi > E) e_hi = E;
    float l = lp[0];

    for (int e = e_lo + g; e < e_hi; e += 256) {
        int s = eli[e];
        int d = eli[E + e];

        uint4 A = posf4[(long)s * 4 + lane];
        uint4 B = posf4[(long)d * 4 + lane];

        float dot = edge_dot(A, B);
        dot += __shfl_xor(dot, 1);
        dot += __shfl_xor(dot, 2);

        if (lane == 0) {
            float na = (float)normT[s] + 32.0f;
            float nb = (float)normT[d] + 32.0f;
            float m  = (float)massT[d] * (1.0f / 4096.0f) - 8.0f;
            float r2 = na + nb - 2.0f * dot;
            if (s == d) r2 = 0.0f;          // self-loops: exact zero distance
            r2 = fmaxf(r2, 0.0f);
            out[e] = m - l * logf(r2 + GRAV_EPS);
        }
    }
}

// ---- Mid-fallback (N too big for LDS): R10 main, nm float2 gather
__global__ __launch_bounds__(256) void grav_main_nm(
    const uint4*  __restrict__ posf4,
    const float2* __restrict__ nm,
    const int*    __restrict__ eli,
    const float*  __restrict__ lp,
    float*        __restrict__ out,
    int E)
{
    int tid  = blockIdx.x * blockDim.x + threadIdx.x;
    int edge = tid >> 2;
    int lane = tid & 3;
    if (edge >= E) return;

    int s = eli[edge];
    int d = eli[E + edge];

    uint4 A = posf4[(long)s * 4 + lane];
    uint4 B = posf4[(long)d * 4 + lane];
    float2 aux = nm[(lane & 1) ? d : s];

    float dot = edge_dot(A, B);
    dot += __shfl_xor(dot, 1);
    dot += __shfl_xor(dot, 2);

    float nb_ = __shfl_xor(aux.x, 1);
    float mb_ = __shfl_xor(aux.y, 1);

    if (lane == 0) {
        float r2 = aux.x + nb_ - 2.0f * dot;
        if (s == d) r2 = 0.0f;
        r2 = fmaxf(r2, 0.0f);
        out[edge] = mb_ - lp[0] * logf(r2 + GRAV_EPS);
    }
}

// ---- fp32 fallback (no workspace)
__global__ __launch_bounds__(256) void grav_fallback_kernel(
    const float* __restrict__ x,
    const int*   __restrict__ eli,
    const float* __restrict__ lp,
    float*       __restrict__ out,
    int E)
{
    const int STRIDE = 129;
    int tid  = blockIdx.x * blockDim.x + threadIdx.x;
    int edge = tid >> 5;
    int lane = tid & 31;
    if (edge >= E) return;
    int s = eli[edge];
    int d = eli[E + edge];
    const float* xs = x + (long)s * STRIDE;
    const float* xd = x + (long)d * STRIDE;
    float sum = 0.0f;
    #pragma unroll
    for (int k = 0; k < 4; ++k) {
        float df = xs[lane + 32 * k] - xd[lane + 32 * k];
        sum = fmaf(df, df, sum);
    }
    sum += __shfl_xor(sum, 1);
    sum += __shfl_xor(sum, 2);
    sum += __shfl_xor(sum, 4);
    sum += __shfl_xor(sum, 8);
    sum += __shfl_xor(sum, 16);
    if (lane == 0) out[edge] = xd[128] - lp[0] * logf(sum + GRAV_EPS);
}

extern "C" void kernel_launch(void* const* d_in, const int* in_sizes, int n_in,
                              void* d_out, int out_size, void* d_ws, size_t ws_size,
                              hipStream_t stream) {
    const float* x   = (const float*)d_in[0];
    const int*   eli = (const int*)d_in[1];
    const float* lp  = (const float*)d_in[2];
    float*       out = (float*)d_out;

    int N = in_sizes[0] / 129;
    int E = in_sizes[1] / 2;

    size_t posf4_b = (size_t)N * 64;
    size_t nm_b    = ((size_t)N * sizeof(float2) + 15) & ~15ull;
    size_t n8_b    = ((size_t)N + 15) & ~15ull;
    size_t m16_b   = ((size_t)N * 2 + 15) & ~15ull;

    if (ws_size >= posf4_b + nm_b + n8_b + m16_b) {
        char* w = (char*)d_ws;
        unsigned int*   posf4   = (unsigned int*)w;    w += posf4_b;
        float2*         nm      = (float2*)w;          w += nm_b;
        unsigned char*  gnorm8  = (unsigned char*)w;   w += n8_b;
        unsigned short* gmass16 = (unsigned short*)w;

        long total_words = (long)N * 16;
        int rblocks = (int)((total_words + 255) / 256);
        grav_repack_fp4<<<rblocks, 256, 0, stream>>>(
            x, posf4, nm, gnorm8, gmass16, total_words, N);

        if (N <= NMAX_LDS) {
            DecoderGravity_33268816675213_kernel<<<256, 1024, 0, stream>>>(
                (const uint4*)posf4, gnorm8, gmass16, eli, lp, out, E, N);
        } else {
            long total = (long)E * 4;
            int blocks = (int)((total + 255) / 256);
            grav_main_nm<<<blocks, 256, 0, stream>>>(
                (const uint4*)posf4, nm, eli, lp, out, E);
        }
    } else {
        long total = (long)E * 32;
        int blocks = (int)((total + 255) / 256);
        grav_fallback_kernel<<<blocks, 256, 0, stream>>>(x, eli, lp, out, E);
    }
}

// Round 13
// 32.139 us; speedup vs baseline: 1.0947x; 1.0947x over previous
//
#include <hip/hip_runtime.h>

#define GRAV_EPS 0.01f
#define NMAX_LDS 50048   // u8 norm table in LDS: 50,048 B -> 2 blocks/CU co-resident

typedef float v2f __attribute__((ext_vector_type(2)));

// e2m1 mag-code -> fp8(e4m3) byte LUT for v_perm:
//  mag {0,0.5,1,1.5, 2,3,4,6} -> {0x00,0x30,0x38,0x3C, 0x40,0x44,0x48,0x4C}
#define T0_LUT 0x3C383000u
#define T1_LUT 0x4C484440u

// ---- Repack: x[N][129] f32 -> posf4[N][64B] e2m1 nibbles
//   + nm[N] float2 {exact norm, mass}        (fallback path)
//   + gnorm8[N] u8 (norm-32), gmass16[N] u16 ((m+8)*4096)
// Scalar x loads only (rows 4B-aligned; float4 casts are UB — R9 lesson).
__global__ __launch_bounds__(256) void grav_repack_fp4(
    const float*    __restrict__ x,
    unsigned int*   __restrict__ posf4,   // N*16 dwords
    float2*         __restrict__ nm,
    unsigned char*  __restrict__ gnorm8,
    unsigned short* __restrict__ gmass16,
    long total_words, int N)
{
    long w = (long)blockIdx.x * blockDim.x + threadIdx.x;
    if (w >= total_words) return;
    int row = (int)(w >> 4);
    int c   = (int)(w & 15);
    const float* src = x + (long)row * 129 + c * 8;

    float nsum = 0.0f;
    unsigned int word = 0;
    #pragma unroll
    for (int j = 0; j < 8; ++j) {
        float v  = src[j];              // scalar, 4B-aligned: well-defined
        nsum = fmaf(v, v, nsum);
        float av = fabsf(v);
        unsigned int m = (av >= 0.25f) + (av >= 0.75f) + (av >= 1.25f) +
                         (av >= 1.75f) + (av >= 2.5f)  + (av >= 3.5f)  +
                         (av >= 5.0f);
        unsigned int nib = m | (v < 0.0f ? 8u : 0u);
        word |= nib << (4 * j);
    }
    posf4[w] = word;

    nsum += __shfl_xor(nsum, 1);
    nsum += __shfl_xor(nsum, 2);
    nsum += __shfl_xor(nsum, 4);
    nsum += __shfl_xor(nsum, 8);
    if (c == 0) {
        float m = x[(long)row * 129 + 128];
        nm[row] = make_float2(nsum, m);
        int nq = (int)rintf(nsum - 32.0f);
        nq = nq < 0 ? 0 : (nq > 255 ? 255 : nq);
        gnorm8[row] = (unsigned char)nq;
        int mq = (int)rintf((m + 8.0f) * 4096.0f);
        mq = mq < 0 ? 0 : (mq > 65535 ? 65535 : mq);
        gmass16[row] = (unsigned short)mq;
    }
}

// Decode one fp4-nibble dword pair and accumulate dot product (8 elems).
__device__ inline void dot_dword(unsigned int wa, unsigned int wb, v2f& acc)
{
    unsigned int ame = wa & 0x07070707u;
    unsigned int amo = (wa >> 4) & 0x07070707u;
    unsigned int ase = (wa & 0x08080808u) << 4;
    unsigned int aso = wa & 0x80808080u;
    unsigned int pae = __builtin_amdgcn_perm(T1_LUT, T0_LUT, ame) | ase;
    unsigned int pao = __builtin_amdgcn_perm(T1_LUT, T0_LUT, amo) | aso;

    unsigned int bme = wb & 0x07070707u;
    unsigned int bmo = (wb >> 4) & 0x07070707u;
    unsigned int bse = (wb & 0x08080808u) << 4;
    unsigned int bso = wb & 0x80808080u;
    unsigned int pbe = __builtin_amdgcn_perm(T1_LUT, T0_LUT, bme) | bse;
    unsigned int pbo = __builtin_amdgcn_perm(T1_LUT, T0_LUT, bmo) | bso;

    v2f a0 = __builtin_amdgcn_cvt_pk_f32_fp8((int)pae, false);
    v2f a1 = __builtin_amdgcn_cvt_pk_f32_fp8((int)pae, true);
    v2f a2 = __builtin_amdgcn_cvt_pk_f32_fp8((int)pao, false);
    v2f a3 = __builtin_amdgcn_cvt_pk_f32_fp8((int)pao, true);
    v2f b0 = __builtin_amdgcn_cvt_pk_f32_fp8((int)pbe, false);
    v2f b1 = __builtin_amdgcn_cvt_pk_f32_fp8((int)pbe, true);
    v2f b2 = __builtin_amdgcn_cvt_pk_f32_fp8((int)pbo, false);
    v2f b3 = __builtin_amdgcn_cvt_pk_f32_fp8((int)pbo, true);

    acc += a0 * b0;
    acc += a1 * b1;
    acc += a2 * b2;
    acc += a3 * b3;
}

__device__ inline float edge_dot(const uint4& A, const uint4& B)
{
    v2f acc = {0.0f, 0.0f};
    dot_dword(A.x, B.x, acc);
    dot_dword(A.y, B.y, acc);
    dot_dword(A.z, B.z, acc);
    dot_dword(A.w, B.w, acc);
    return acc.x + acc.y;
}

// ---- Main: norm table (u8, 50KB) in LDS; 1024-thread blocks, 2 blocks/CU
// co-resident (100KB LDS, 2048 thr) -> full 32 waves/CU. Per edge: 2 row
// granules + 1 mass granule (was 4.2 in R10).
__global__ __launch_bounds__(1024, 8) void DecoderGravity_33268816675213_kernel(
    const uint4*          __restrict__ posf4,
    const unsigned char*  __restrict__ gnorm8,
    const unsigned short* __restrict__ gmass16,
    const int*            __restrict__ eli,
    const float*          __restrict__ lp,
    float*                __restrict__ out,
    int E, int N)
{
    __shared__ unsigned char normT[NMAX_LDS];

    for (int i = threadIdx.x; i < N; i += 1024) normT[i] = gnorm8[i];
    __syncthreads();

    int lane = threadIdx.x & 3;
    int g    = threadIdx.x >> 2;            // 0..255 edge-groups per block
    int chunk = (E + (int)gridDim.x - 1) / (int)gridDim.x;
    int e_lo = (int)blockIdx.x * chunk;
    int e_hi = e_lo + chunk; if (e_hi > E) e_hi = E;
    float l = lp[0];

    for (int e = e_lo + g; e < e_hi; e += 256) {
        int s = eli[e];
        int d = eli[E + e];

        uint4 A = posf4[(long)s * 4 + lane];
        uint4 B = posf4[(long)d * 4 + lane];

        // lane 0 fetches mass early (1 random granule, overlaps decode)
        float m = 0.0f;
        if (lane == 0) m = (float)gmass16[d] * (1.0f / 4096.0f) - 8.0f;

        float dot = edge_dot(A, B);
        dot += __shfl_xor(dot, 1);
        dot += __shfl_xor(dot, 2);

        if (lane == 0) {
            float na = (float)normT[s] + 32.0f;
            float nb = (float)normT[d] + 32.0f;
            float r2 = na + nb - 2.0f * dot;
            if (s == d) r2 = 0.0f;          // self-loops: exact zero distance
            r2 = fmaxf(r2, 0.0f);
            out[e] = m - l * logf(r2 + GRAV_EPS);
        }
    }
}

// ---- Mid-fallback (N too big for LDS): R10 main, nm float2 gather
__global__ __launch_bounds__(256) void grav_main_nm(
    const uint4*  __restrict__ posf4,
    const float2* __restrict__ nm,
    const int*    __restrict__ eli,
    const float*  __restrict__ lp,
    float*        __restrict__ out,
    int E)
{
    int tid  = blockIdx.x * blockDim.x + threadIdx.x;
    int edge = tid >> 2;
    int lane = tid & 3;
    if (edge >= E) return;

    int s = eli[edge];
    int d = eli[E + edge];

    uint4 A = posf4[(long)s * 4 + lane];
    uint4 B = posf4[(long)d * 4 + lane];
    float2 aux = nm[(lane & 1) ? d : s];

    float dot = edge_dot(A, B);
    dot += __shfl_xor(dot, 1);
    dot += __shfl_xor(dot, 2);

    float nb_ = __shfl_xor(aux.x, 1);
    float mb_ = __shfl_xor(aux.y, 1);

    if (lane == 0) {
        float r2 = aux.x + nb_ - 2.0f * dot;
        if (s == d) r2 = 0.0f;
        r2 = fmaxf(r2, 0.0f);
        out[edge] = mb_ - lp[0] * logf(r2 + GRAV_EPS);
    }
}

// ---- fp32 fallback (no workspace)
__global__ __launch_bounds__(256) void grav_fallback_kernel(
    const float* __restrict__ x,
    const int*   __restrict__ eli,
    const float* __restrict__ lp,
    float*       __restrict__ out,
    int E)
{
    const int STRIDE = 129;
    int tid  = blockIdx.x * blockDim.x + threadIdx.x;
    int edge = tid >> 5;
    int lane = tid & 31;
    if (edge >= E) return;
    int s = eli[edge];
    int d = eli[E + edge];
    const float* xs = x + (long)s * STRIDE;
    const float* xd = x + (long)d * STRIDE;
    float sum = 0.0f;
    #pragma unroll
    for (int k = 0; k < 4; ++k) {
        float df = xs[lane + 32 * k] - xd[lane + 32 * k];
        sum = fmaf(df, df, sum);
    }
    sum += __shfl_xor(sum, 1);
    sum += __shfl_xor(sum, 2);
    sum += __shfl_xor(sum, 4);
    sum += __shfl_xor(sum, 8);
    sum += __shfl_xor(sum, 16);
    if (lane == 0) out[edge] = xd[128] - lp[0] * logf(sum + GRAV_EPS);
}

extern "C" void kernel_launch(void* const* d_in, const int* in_sizes, int n_in,
                              void* d_out, int out_size, void* d_ws, size_t ws_size,
                              hipStream_t stream) {
    const float* x   = (const float*)d_in[0];
    const int*   eli = (const int*)d_in[1];
    const float* lp  = (const float*)d_in[2];
    float*       out = (float*)d_out;

    int N = in_sizes[0] / 129;
    int E = in_sizes[1] / 2;

    size_t posf4_b = (size_t)N * 64;
    size_t nm_b    = ((size_t)N * sizeof(float2) + 15) & ~15ull;
    size_t n8_b    = ((size_t)N + 15) & ~15ull;
    size_t m16_b   = ((size_t)N * 2 + 15) & ~15ull;

    if (ws_size >= posf4_b + nm_b + n8_b + m16_b) {
        char* w = (char*)d_ws;
        unsigned int*   posf4   = (unsigned int*)w;    w += posf4_b;
        float2*         nm      = (float2*)w;          w += nm_b;
        unsigned char*  gnorm8  = (unsigned char*)w;   w += n8_b;
        unsigned short* gmass16 = (unsigned short*)w;

        long total_words = (long)N * 16;
        int rblocks = (int)((total_words + 255) / 256);
        grav_repack_fp4<<<rblocks, 256, 0, stream>>>(
            x, posf4, nm, gnorm8, gmass16, total_words, N);

        if (N <= NMAX_LDS) {
            // 512 blocks x 1024 thr: 2 blocks/CU co-resident (100KB LDS), 32 waves/CU
            DecoderGravity_33268816675213_kernel<<<512, 1024, 0, stream>>>(
                (const uint4*)posf4, gnorm8, gmass16, eli, lp, out, E, N);
        } else {
            long total = (long)E * 4;
            int blocks = (int)((total + 255) / 256);
            grav_main_nm<<<blocks, 256, 0, stream>>>(
                (const uint4*)posf4, nm, eli, lp, out, E);
        }
    } else {
        long total = (long)E * 32;
        int blocks = (int)((total + 255) / 256);
        grav_fallback_kernel<<<blocks, 256, 0, stream>>>(x, eli, lp, out, E);
    }
}

// Round 14
// 29.395 us; speedup vs baseline: 1.1969x; 1.0933x over previous
//
#include <hip/hip_runtime.h>

#define GRAV_EPS 0.01f

// ---- Repack: x[N][129] f32 -> q8[N][128B] biased-u8 (q=clamp(round(v*16),-63,63)+64)
//              + massT[N] f32
// One thread per output dword (4 elems). 32 threads per row. Scalar x loads
// (rows 4B-aligned; vector casts are UB — R9 lesson).
__global__ __launch_bounds__(256) void grav_repack_q8(
    const float*  __restrict__ x,
    unsigned int* __restrict__ q8,      // N*32 dwords
    float*        __restrict__ massT,
    long total_words, int N)
{
    long w = (long)blockIdx.x * blockDim.x + threadIdx.x;
    if (w >= total_words) return;
    int row = (int)(w >> 5);
    int c   = (int)(w & 31);            // dword index, covers elems 4c..4c+3
    const float* src = x + (long)row * 129 + c * 4;

    unsigned int word = 0;
    #pragma unroll
    for (int j = 0; j < 4; ++j) {
        float v = src[j];
        int q = (int)rintf(v * 16.0f);
        q = q < -63 ? -63 : (q > 63 ? 63 : q);
        word |= (unsigned int)(q + 64) << (8 * j);
    }
    q8[w] = word;
    if (c == 0) massT[row] = x[(long)row * 129 + 128];
}

// ---- Main: 4 lanes/edge, 32B (8 dwords) per lane = 128B row.
// SWAR diff + udot4: per dword {or, sub, udot4(x,x), udot4(x,1)} = 1 op/elem.
// Sum(x-128)^2 = S2 - 256*S1 + 128*128*128 (integer exact); r2 = that / 256.
__global__ __launch_bounds__(256) void DecoderGravity_33268816675213_kernel(
    const uint4* __restrict__ q8,       // N rows x 8 uint4 (2 uint4 per lane)
    const float* __restrict__ massT,
    const int*   __restrict__ eli,
    const float* __restrict__ lp,
    float*       __restrict__ out,
    int E)
{
    int tid  = blockIdx.x * blockDim.x + threadIdx.x;
    int edge = tid >> 2;
    int lane = tid & 3;
    if (edge >= E) return;

    int s = eli[edge];
    int d = eli[E + edge];

    // lane L covers bytes [L*16, L*16+16) and [64+L*16, 64+L*16+16)
    const uint4* rs = q8 + (long)s * 8;
    const uint4* rd = q8 + (long)d * 8;
    uint4 A0 = rs[lane];
    uint4 A1 = rs[lane + 4];
    uint4 B0 = rd[lane];
    uint4 B1 = rd[lane + 4];

    // mass fetched early by lane 0 (overlaps integer math)
    float m = 0.0f;
    if (lane == 0) m = massT[d];

    unsigned int s2 = 0, s1 = 0;
    const unsigned int HB = 0x80808080u;
    const unsigned int ONES = 0x01010101u;
    {
        unsigned int xw;
        xw = (A0.x | HB) - B0.x; s2 = __builtin_amdgcn_udot4(xw, xw, s2, false);
                                 s1 = __builtin_amdgcn_udot4(xw, ONES, s1, false);
        xw = (A0.y | HB) - B0.y; s2 = __builtin_amdgcn_udot4(xw, xw, s2, false);
                                 s1 = __builtin_amdgcn_udot4(xw, ONES, s1, false);
        xw = (A0.z | HB) - B0.z; s2 = __builtin_amdgcn_udot4(xw, xw, s2, false);
                                 s1 = __builtin_amdgcn_udot4(xw, ONES, s1, false);
        xw = (A0.w | HB) - B0.w; s2 = __builtin_amdgcn_udot4(xw, xw, s2, false);
                                 s1 = __builtin_amdgcn_udot4(xw, ONES, s1, false);
        xw = (A1.x | HB) - B1.x; s2 = __builtin_amdgcn_udot4(xw, xw, s2, false);
                                 s1 = __builtin_amdgcn_udot4(xw, ONES, s1, false);
        xw = (A1.y | HB) - B1.y; s2 = __builtin_amdgcn_udot4(xw, xw, s2, false);
                                 s1 = __builtin_amdgcn_udot4(xw, ONES, s1, false);
        xw = (A1.z | HB) - B1.z; s2 = __builtin_amdgcn_udot4(xw, xw, s2, false);
                                 s1 = __builtin_amdgcn_udot4(xw, ONES, s1, false);
        xw = (A1.w | HB) - B1.w; s2 = __builtin_amdgcn_udot4(xw, xw, s2, false);
                                 s1 = __builtin_amdgcn_udot4(xw, ONES, s1, false);
    }

    // reduce S2, S1 across the 4-lane group
    s2 += __shfl_xor((int)s2, 1);
    s2 += __shfl_xor((int)s2, 2);
    s1 += __shfl_xor((int)s1, 1);
    s1 += __shfl_xor((int)s1, 2);

    if (lane == 0) {
        // Sum d_q^2 = s2 - 256*s1 + 128*128*128  (128 elems, bias 128)
        int sq = (int)s2 - ((int)s1 << 8) + 2097152;
        float r2 = (float)sq * (1.0f / 256.0f);
        out[edge] = m - lp[0] * logf(r2 + GRAV_EPS);
    }
}

// ---- fp32 fallback (no workspace)
__global__ __launch_bounds__(256) void grav_fallback_kernel(
    const float* __restrict__ x,
    const int*   __restrict__ eli,
    const float* __restrict__ lp,
    float*       __restrict__ out,
    int E)
{
    const int STRIDE = 129;
    int tid  = blockIdx.x * blockDim.x + threadIdx.x;
    int edge = tid >> 5;
    int lane = tid & 31;
    if (edge >= E) return;
    int s = eli[edge];
    int d = eli[E + edge];
    const float* xs = x + (long)s * STRIDE;
    const float* xd = x + (long)d * STRIDE;
    float sum = 0.0f;
    #pragma unroll
    for (int k = 0; k < 4; ++k) {
        float df = xs[lane + 32 * k] - xd[lane + 32 * k];
        sum = fmaf(df, df, sum);
    }
    sum += __shfl_xor(sum, 1);
    sum += __shfl_xor(sum, 2);
    sum += __shfl_xor(sum, 4);
    sum += __shfl_xor(sum, 8);
    sum += __shfl_xor(sum, 16);
    if (lane == 0) out[edge] = xd[128] - lp[0] * logf(sum + GRAV_EPS);
}

extern "C" void kernel_launch(void* const* d_in, const int* in_sizes, int n_in,
                              void* d_out, int out_size, void* d_ws, size_t ws_size,
                              hipStream_t stream) {
    const float* x   = (const float*)d_in[0];
    const int*   eli = (const int*)d_in[1];
    const float* lp  = (const float*)d_in[2];
    float*       out = (float*)d_out;

    int N = in_sizes[0] / 129;
    int E = in_sizes[1] / 2;

    size_t q8_b   = (size_t)N * 128;                 // 128 B per row
    size_t mass_b = ((size_t)N * 4 + 15) & ~15ull;

    if (ws_size >= q8_b + mass_b) {
        unsigned int* q8    = (unsigned int*)d_ws;
        float*        massT = (float*)((char*)d_ws + q8_b);

        long total_words = (long)N * 32;
        int rblocks = (int)((total_words + 255) / 256);
        grav_repack_q8<<<rblocks, 256, 0, stream>>>(x, q8, massT, total_words, N);

        long total = (long)E * 4;
        int blocks = (int)((total + 255) / 256);
        DecoderGravity_33268816675213_kernel<<<blocks, 256, 0, stream>>>(
            (const uint4*)q8, massT, eli, lp, out, E);
    } else {
        long total = (long)E * 32;
        int blocks = (int)((total + 255) / 256);
        grav_fallback_kernel<<<blocks, 256, 0, stream>>>(x, eli, lp, out, E);
    }
}

// Round 15
// 28.587 us; speedup vs baseline: 1.2308x; 1.0283x over previous
//
#include <hip/hip_runtime.h>

#define GRAV_EPS 0.01f

typedef float v2f __attribute__((ext_vector_type(2)));

// e2m1 mag-code -> fp8(e4m3) byte LUT for v_perm:
//  mag {0,0.5,1,1.5, 2,3,4,6} -> {0x00,0x30,0x38,0x3C, 0x40,0x44,0x48,0x4C}
#define T0_LUT 0x3C383000u
#define T1_LUT 0x4C484440u

// ---- Repack: x[N][129] f32 -> posf4[N][64B] e2m1 nibbles + massT[N] f32
// One thread per output dword (8 elems). 16 threads per row.
// Scalar x loads only (rows 4B-aligned; vector casts are UB — R9 lesson).
__global__ __launch_bounds__(256) void grav_repack_fp4(
    const float*  __restrict__ x,
    unsigned int* __restrict__ posf4,   // N*16 dwords
    float*        __restrict__ massT,
    long total_words, int N)
{
    long w = (long)blockIdx.x * blockDim.x + threadIdx.x;
    if (w >= total_words) return;
    int row = (int)(w >> 4);
    int c   = (int)(w & 15);
    const float* src = x + (long)row * 129 + c * 8;

    unsigned int word = 0;
    #pragma unroll
    for (int j = 0; j < 8; ++j) {
        float v  = src[j];              // scalar, 4B-aligned: well-defined
        float av = fabsf(v);
        // e2m1 RTNE boundaries: 0.25,0.75,1.25,1.75,2.5,3.5,5.0
        unsigned int m = (av >= 0.25f) + (av >= 0.75f) + (av >= 1.25f) +
                         (av >= 1.75f) + (av >= 2.5f)  + (av >= 3.5f)  +
                         (av >= 5.0f);
        unsigned int nib = m | (v < 0.0f ? 8u : 0u);
        word |= nib << (4 * j);
    }
    posf4[w] = word;
    if (c == 0) massT[row] = x[(long)row * 129 + 128];
}

// Decode one fp4-nibble dword pair; accumulate squared diff (8 elems).
__device__ inline void diff_dword(unsigned int wa, unsigned int wb, v2f& acc)
{
    unsigned int ame = wa & 0x07070707u;
    unsigned int amo = (wa >> 4) & 0x07070707u;
    unsigned int ase = (wa & 0x08080808u) << 4;
    unsigned int aso = wa & 0x80808080u;
    unsigned int pae = __builtin_amdgcn_perm(T1_LUT, T0_LUT, ame) | ase;
    unsigned int pao = __builtin_amdgcn_perm(T1_LUT, T0_LUT, amo) | aso;

    unsigned int bme = wb & 0x07070707u;
    unsigned int bmo = (wb >> 4) & 0x07070707u;
    unsigned int bse = (wb & 0x08080808u) << 4;
    unsigned int bso = wb & 0x80808080u;
    unsigned int pbe = __builtin_amdgcn_perm(T1_LUT, T0_LUT, bme) | bse;
    unsigned int pbo = __builtin_amdgcn_perm(T1_LUT, T0_LUT, bmo) | bso;

    v2f d0 = __builtin_amdgcn_cvt_pk_f32_fp8((int)pae, false)
           - __builtin_amdgcn_cvt_pk_f32_fp8((int)pbe, false);
    v2f d1 = __builtin_amdgcn_cvt_pk_f32_fp8((int)pae, true)
           - __builtin_amdgcn_cvt_pk_f32_fp8((int)pbe, true);
    v2f d2 = __builtin_amdgcn_cvt_pk_f32_fp8((int)pao, false)
           - __builtin_amdgcn_cvt_pk_f32_fp8((int)pbo, false);
    v2f d3 = __builtin_amdgcn_cvt_pk_f32_fp8((int)pao, true)
           - __builtin_amdgcn_cvt_pk_f32_fp8((int)pbo, true);

    acc += d0 * d0;
    acc += d1 * d1;
    acc += d2 * d2;
    acc += d3 * d3;
}

// ---- Main: 4 lanes/edge, one uint4 (32 fp4) per lane = whole 64B row.
// Direct squared-diff (no norm decomposition): per edge only 2 row granules
// + 1 mass granule. Self-loops are exact (identical rows -> diff 0).
__global__ __launch_bounds__(256) void DecoderGravity_33268816675213_kernel(
    const uint4* __restrict__ posf4,    // N rows x 4 uint4
    const float* __restrict__ massT,
    const int*   __restrict__ eli,
    const float* __restrict__ lp,
    float*       __restrict__ out,
    int E)
{
    int tid  = blockIdx.x * blockDim.x + threadIdx.x;
    int edge = tid >> 2;
    int lane = tid & 3;
    if (edge >= E) return;

    int s = eli[edge];
    int d = eli[E + edge];

    uint4 A = posf4[(long)s * 4 + lane];
    uint4 B = posf4[(long)d * 4 + lane];

    // lane 0 fetches mass early (overlaps decode)
    float m = 0.0f;
    if (lane == 0) m = massT[d];

    v2f acc = {0.0f, 0.0f};
    diff_dword(A.x, B.x, acc);
    diff_dword(A.y, B.y, acc);
    diff_dword(A.z, B.z, acc);
    diff_dword(A.w, B.w, acc);
    float sum = acc.x + acc.y;

    sum += __shfl_xor(sum, 1);
    sum += __shfl_xor(sum, 2);

    if (lane == 0) {
        out[edge] = m - lp[0] * logf(sum + GRAV_EPS);
    }
}

// ---- fp32 fallback (no workspace)
__global__ __launch_bounds__(256) void grav_fallback_kernel(
    const float* __restrict__ x,
    const int*   __restrict__ eli,
    const float* __restrict__ lp,
    float*       __restrict__ out,
    int E)
{
    const int STRIDE = 129;
    int tid  = blockIdx.x * blockDim.x + threadIdx.x;
    int edge = tid >> 5;
    int lane = tid & 31;
    if (edge >= E) return;
    int s = eli[edge];
    int d = eli[E + edge];
    const float* xs = x + (long)s * STRIDE;
    const float* xd = x + (long)d * STRIDE;
    float sum = 0.0f;
    #pragma unroll
    for (int k = 0; k < 4; ++k) {
        float df = xs[lane + 32 * k] - xd[lane + 32 * k];
        sum = fmaf(df, df, sum);
    }
    sum += __shfl_xor(sum, 1);
    sum += __shfl_xor(sum, 2);
    sum += __shfl_xor(sum, 4);
    sum += __shfl_xor(sum, 8);
    sum += __shfl_xor(sum, 16);
    if (lane == 0) out[edge] = xd[128] - lp[0] * logf(sum + GRAV_EPS);
}

extern "C" void kernel_launch(void* const* d_in, const int* in_sizes, int n_in,
                              void* d_out, int out_size, void* d_ws, size_t ws_size,
                              hipStream_t stream) {
    const float* x   = (const float*)d_in[0];
    const int*   eli = (const int*)d_in[1];
    const float* lp  = (const float*)d_in[2];
    float*       out = (float*)d_out;

    int N = in_sizes[0] / 129;
    int E = in_sizes[1] / 2;

    size_t posf4_b = (size_t)N * 64;                 // 64 B per row
    size_t mass_b  = ((size_t)N * 4 + 15) & ~15ull;

    if (ws_size >= posf4_b + mass_b) {
        unsigned int* posf4 = (unsigned int*)d_ws;
        float*        massT = (float*)((char*)d_ws + posf4_b);

        long total_words = (long)N * 16;
        int rblocks = (int)((total_words + 255) / 256);
        grav_repack_fp4<<<rblocks, 256, 0, stream>>>(x, posf4, massT, total_words, N);

        long total = (long)E * 4;
        int blocks = (int)((total + 255) / 256);
        DecoderGravity_33268816675213_kernel<<<blocks, 256, 0, stream>>>(
            (const uint4*)posf4, massT, eli, lp, out, E);
    } else {
        long total = (long)E * 32;
        int blocks = (int)((total + 255) / 256);
        grav_fallback_kernel<<<blocks, 256, 0, stream>>>(x, eli, lp, out, E);
    }
}